// Round 5
// baseline (52.917 us; speedup 1.0000x reference)
//
#include <hip/hip_runtime.h>

#define WT_L0 8192
#define WT_NT 512

typedef float f4 __attribute__((ext_vector_type(4)));
typedef float f2 __attribute__((ext_vector_type(2)));

// LDS (floats), peak 32 KB:
//   sig1  [0,4096)    (dead after P2; down2 reuses [0,1024))
//   down1 [4096,6144)
//   sig2  [6144,8192)

__global__ __launch_bounds__(WT_NT) void wavelet1d_kernel(
    const float* __restrict__ x,
    const float* __restrict__ w0,
    const float* __restrict__ w1,
    const float* __restrict__ w2,
    float* __restrict__ out)
{
    __shared__ float buf[8192];
    const int row = blockIdx.x;
    const int t = threadIdx.x;
    const float* __restrict__ xr = x + (size_t)row * WT_L0;
    float* __restrict__ outr = out + (size_t)row * 3 * WT_L0;

    float f0[3], f1[5], f2a[7];
    #pragma unroll
    for (int k = 0; k < 3; ++k) f0[k] = w0[k];
    #pragma unroll
    for (int k = 0; k < 5; ++k) f1[k] = w1[k];
    #pragma unroll
    for (int k = 0; k < 7; ++k) f2a[k] = w2[k];

    // composed pool∘conv5 (stride-2, 6-tap) and pool∘conv7 (stride-2, 8-tap)
    const float g0 = 0.5f*f1[0], g1 = 0.5f*(f1[0]+f1[1]), g2 = 0.5f*(f1[1]+f1[2]),
                g3 = 0.5f*(f1[2]+f1[3]), g4 = 0.5f*(f1[3]+f1[4]), g5 = 0.5f*f1[4];
    const float h0 = 0.5f*f2a[0], h1 = 0.5f*(f2a[0]+f2a[1]), h2 = 0.5f*(f2a[1]+f2a[2]),
                h3 = 0.5f*(f2a[2]+f2a[3]), h4 = 0.5f*(f2a[3]+f2a[4]),
                h5 = 0.5f*(f2a[4]+f2a[5]), h6 = 0.5f*(f2a[5]+f2a[6]), h7 = 0.5f*f2a[6];

    // ---- P1: conv3 -> out0 (pure regs) ; sig1 = pool(x) ----
    {
        const f4* __restrict__ xr4 = (const f4*)xr;
        f4* __restrict__ out0_4 = (f4*)outr;
        f2* sig1_2 = (f2*)buf;
        #pragma unroll
        for (int c = 0; c < 4; ++c) {
            int q = t + 512 * c;                       // f4 index, 0..2047
            f4 v = __builtin_nontemporal_load(&xr4[q]);
            float lm = (q > 0)    ? xr[4 * q - 1] : 0.f;
            float rp = (q < 2047) ? xr[4 * q + 4] : 0.f;
            f4 o;
            o.x = f0[0]*lm  + f0[1]*v.x + f0[2]*v.y;
            o.y = f0[0]*v.x + f0[1]*v.y + f0[2]*v.z;
            o.z = f0[0]*v.y + f0[1]*v.z + f0[2]*v.w;
            o.w = f0[0]*v.z + f0[1]*v.w + f0[2]*rp;
            __builtin_nontemporal_store(o, &out0_4[q]);
            f2 s; s.x = 0.5f * (v.x + v.y); s.y = 0.5f * (v.z + v.w);
            sig1_2[q] = s;                             // sig1[2q..2q+2)
        }
    }
    __syncthreads();

    const float* sig1   = buf;
    const f4*    sig1_4 = (const f4*)sig1;

    // ---- P2: down1 = (pool∘conv5)(sig1) -> [4096,6144); sig2 = pool(sig1) -> [6144,8192) ----
    {
        f2* down1_2 = (f2*)(buf + 4096);
        f2* sig2_2  = (f2*)(buf + 6144);
        #pragma unroll
        for (int c = 0; c < 2; ++c) {
            int j = t + 512 * c;                       // 0..1023
            f4 v = sig1_4[j];                          // sig1[4j..4j+4)
            f2 lf = (j > 0)    ? *(const f2*)&sig1[4 * j - 2] : (f2)(0.f);  // zero-pad (conv)
            f2 rf = (j < 1023) ? *(const f2*)&sig1[4 * j + 4] : (f2)(0.f);
            f2 d;
            d.x = g0*lf.x + g1*lf.y + g2*v.x + g3*v.y + g4*v.z + g5*v.w;   // down1[2j]
            d.y = g0*v.x  + g1*v.y  + g2*v.z + g3*v.w + g4*rf.x + g5*rf.y; // down1[2j+1]
            down1_2[j] = d;
            f2 s; s.x = 0.5f * (v.x + v.y); s.y = 0.5f * (v.z + v.w);
            sig2_2[j] = s;                             // sig2[2j..2j+2)
        }
    }
    __syncthreads();

    const float* down1 = buf + 4096;
    const float* sig2  = buf + 6144;

    // ---- P3: out1 = up2(up2(down1)) -> global ; down2 = (pool∘conv7)(sig2) -> [0,1024) ----
    {
        f4* __restrict__ out1_4 = (f4*)(outr + WT_L0);
        #pragma unroll
        for (int c = 0; c < 4; ++c) {
            int q = t + 512 * c;                       // 0..2047 (== m)
            float d0  = down1[q];
            float dm1 = (q > 0)    ? down1[q - 1] : d0;   // interp edge-replicate
            float d1  = (q < 2047) ? down1[q + 1] : d0;
            f4 o;
            o.x = 0.375f  * dm1 + 0.625f * d0;
            o.y = 0.1875f * dm1 + 0.75f  * d0 + 0.0625f * d1;
            o.z = 0.0625f * dm1 + 0.75f  * d0 + 0.1875f * d1;
            o.w = 0.625f  * d0  + 0.375f * d1;
            __builtin_nontemporal_store(o, &out1_4[q]);
        }
        float* down2 = buf;                            // sig1 region dead
        #pragma unroll
        for (int c = 0; c < 2; ++c) {
            int j = t + 512 * c;                       // 0..1023
            int base = 2 * j - 3;
            float s0 = (base + 0 >= 0)   ? sig2[base + 0] : 0.f;   // zero-pad (conv)
            float s1 = (base + 1 >= 0)   ? sig2[base + 1] : 0.f;
            float s2 = (base + 2 >= 0)   ? sig2[base + 2] : 0.f;
            float s3 = sig2[base + 3];
            float s4 = sig2[base + 4];
            float s5 = (base + 5 < 2048) ? sig2[base + 5] : 0.f;
            float s6 = (base + 6 < 2048) ? sig2[base + 6] : 0.f;
            float s7 = (base + 7 < 2048) ? sig2[base + 7] : 0.f;
            down2[j] = h0*s0 + h1*s1 + h2*s2 + h3*s3 + h4*s4 + h5*s5 + h6*s6 + h7*s7;
        }
    }
    __syncthreads();

    const float* down2 = buf;

    // ---- P4: out2 = (up4∘up2)(down2) -> global ----
    {
        f4* __restrict__ out2_4 = (f4*)(outr + 2 * WT_L0);
        #pragma unroll
        for (int c = 0; c < 4; ++c) {
            int q = t + 512 * c;                       // 0..2047
            int m = q >> 1;
            int p = q & 1;
            float d0  = down2[m];
            float dm1 = (m > 0)    ? down2[m - 1] : d0;
            float d1  = (m < 1023) ? down2[m + 1] : d0;
            f4 wa = p ? (f4){0.09375f, 0.03125f, 0.f,      0.f     }
                      : (f4){0.4375f,  0.3125f,  0.21875f, 0.15625f};
            f4 wb = p ? (f4){0.75f,    0.75f,    0.6875f,  0.5625f }
                      : (f4){0.5625f,  0.6875f,  0.75f,    0.75f   };
            f4 wc = p ? (f4){0.15625f, 0.21875f, 0.3125f,  0.4375f }
                      : (f4){0.f,      0.f,      0.03125f, 0.09375f};
            f4 o = wa * dm1 + wb * d0 + wc * d1;
            __builtin_nontemporal_store(o, &out2_4[q]);
        }
    }
}

extern "C" void kernel_launch(void* const* d_in, const int* in_sizes, int n_in,
                              void* d_out, int out_size, void* d_ws, size_t ws_size,
                              hipStream_t stream) {
    const float* x  = (const float*)d_in[0];
    const float* w0 = (const float*)d_in[1];
    const float* w1 = (const float*)d_in[2];
    const float* w2 = (const float*)d_in[3];
    float* out = (float*)d_out;

    const int rows = in_sizes[0] / WT_L0;     // B*C = 2048
    wavelet1d_kernel<<<dim3(rows), dim3(WT_NT), 0, stream>>>(x, w0, w1, w2, out);
}